// Round 1
// baseline (753.852 us; speedup 1.0000x reference)
//
#include <hip/hip_runtime.h>

typedef short s8v __attribute__((ext_vector_type(8)));
typedef float f4v __attribute__((ext_vector_type(4)));

#define NTOK 49
// ONE LDS staging buffer fp32 [49][132]; wave w owns cols [32w, 32w+32).
// Sequential wave-private reuse (same-wave DS ops are in-order, no barriers needed):
//   V -> (Vb regs) -> Q -> (Q frags) -> K -> (K frags) -> P(bf16 u16) -> attn_out(hi/lo u16)
// Cross-wave handoff only at attn_out (single barrier before proj).
#define LDS_RT   6468     // [49] 0.17678/T
#define LDS_UB   6517     // [49] relu(u_bias)
#define LDS_GATE 6566     // [4][49]
#define LDS_TOT  6762     // 27048 B -> 27648 alloc; LDS cap 5 blk/CU, reg target 4 waves/SIMD

// ws byte layout: qkv_hi u16[49152] @0 ; qkv_lo @98304 ; proj_hi u16[16384] @196608 ;
//                 proj_lo @229376 ; bias f32[4][49][49] @262144
#define WS_BIAS_OFF 262144

__device__ __forceinline__ unsigned short f2bf(float f){          // RNE
    unsigned x = __float_as_uint(f);
    x += 0x7fffu + ((x >> 16) & 1u);
    return (unsigned short)(x >> 16);
}
// truncation split: hi = top16(f), lo = top16(f - hi). err <= 2^-16 |f|
__device__ __forceinline__ void split8t(const float* f, s8v& hi, s8v& lo){
    #pragma unroll
    for (int j = 0; j < 8; ++j){
        unsigned u = __float_as_uint(f[j]);
        hi[j] = (short)(u >> 16);
        float r = f[j] - __uint_as_float(u & 0xffff0000u);
        lo[j] = (short)(__float_as_uint(r) >> 16);
    }
}

__global__ void prep_kernel(const float* __restrict__ qkv_w, const float* __restrict__ proj_w,
                            const float* __restrict__ rel_table, const int* __restrict__ rel_index,
                            void* __restrict__ ws){
    int i = blockIdx.x * 256 + threadIdx.x;
    unsigned short* qh = (unsigned short*)ws;
    unsigned short* ql = qh + 49152;
    unsigned short* ph = (unsigned short*)((char*)ws + 196608);
    unsigned short* pl = (unsigned short*)((char*)ws + 229376);
    float* biasT = (float*)((char*)ws + WS_BIAS_OFF);
    if (i < 49152){
        float v = qkv_w[i];
        unsigned u = __float_as_uint(v);
        qh[i] = (unsigned short)(u >> 16);
        ql[i] = (unsigned short)(__float_as_uint(v - __uint_as_float(u & 0xffff0000u)) >> 16);
    } else if (i < 65536){
        int j = i - 49152;
        float v = proj_w[j];
        unsigned u = __float_as_uint(v);
        ph[j] = (unsigned short)(u >> 16);
        pl[j] = (unsigned short)(__float_as_uint(v - __uint_as_float(u & 0xffff0000u)) >> 16);
    } else if (i < 75140){
        int j = i - 65536;
        int h = j / 2401, r = j % 2401;       // r = q*49 + k
        biasT[h*2401 + r] = rel_table[rel_index[r]*4 + h];
    }
}

#define MFMA(a,b,c) __builtin_amdgcn_mfma_f32_16x16x32_bf16((a),(b),(c),0,0,0)

// One QKV output group: wave w's 32 cols of {q|k|v} for all 49 rows, split-bf16
// 3-MFMA GEMM, staged into the wave's LDS slice. scaleq folds (1/sqrt32)/T into q.
// gbase: 0=q, 8=k, 16=v (16-col tile index base).
__device__ __forceinline__ void qkv_pass(const float* __restrict__ x,
        const unsigned short* __restrict__ qkh, const unsigned short* __restrict__ qkl,
        const float* __restrict__ qkv_b, float* sm,
        int b, int w, int lc, int q4, int gbase, bool scaleq)
{
    #pragma unroll
    for (int mp = 0; mp < 2; ++mp){
        s8v ah[2][4], al[2][4];
        #pragma unroll
        for (int m2 = 0; m2 < 2; ++m2){
            int row = (mp*2 + m2)*16 + lc; if (row > 48) row = 48;
            const float* xp = x + ((size_t)b*NTOK + row)*128 + q4*8;
            #pragma unroll
            for (int kf = 0; kf < 4; ++kf){
                float xv[8];
                float4 t0 = *(const float4*)(xp + kf*32);
                float4 t1 = *(const float4*)(xp + kf*32 + 4);
                xv[0]=t0.x; xv[1]=t0.y; xv[2]=t0.z; xv[3]=t0.w;
                xv[4]=t1.x; xv[5]=t1.y; xv[6]=t1.z; xv[7]=t1.w;
                split8t(xv, ah[m2][kf], al[m2][kf]);
            }
        }
        #pragma unroll
        for (int t = 0; t < 2; ++t){
            int col = (gbase + 2*w + t)*16 + lc;
            float bia = qkv_b[col];
            f4v acc0 = {bia, bia, bia, bia};
            f4v acc1 = {bia, bia, bia, bia};
            #pragma unroll
            for (int kf = 0; kf < 4; ++kf){
                int off = col*128 + kf*32 + q4*8;
                s8v bh = *(const s8v*)(qkh + off);
                s8v bl = *(const s8v*)(qkl + off);
                acc0 = MFMA(ah[0][kf], bh, acc0);
                acc0 = MFMA(ah[0][kf], bl, acc0);
                acc0 = MFMA(al[0][kf], bh, acc0);
                acc1 = MFMA(ah[1][kf], bh, acc1);
                acc1 = MFMA(ah[1][kf], bl, acc1);
                acc1 = MFMA(al[1][kf], bh, acc1);
            }
            #pragma unroll
            for (int m2 = 0; m2 < 2; ++m2){
                f4v acc = m2 ? acc1 : acc0;
                #pragma unroll
                for (int r = 0; r < 4; ++r){
                    int row = (mp*2 + m2)*16 + q4*4 + r;
                    if (row < NTOK){
                        float v = acc[r];
                        if (scaleq) v *= sm[LDS_RT + row];
                        sm[row*132 + w*32 + t*16 + lc] = v;
                    }
                }
            }
        }
    }
}

__global__ __launch_bounds__(256, 4)
void win_attn(const float* __restrict__ x, const float* __restrict__ u_temp,
              const float* __restrict__ u_bias, const float* __restrict__ gate,
              const float* __restrict__ qkv_b, const float* __restrict__ proj_b,
              const void* __restrict__ ws, float* __restrict__ out)
{
    __shared__ float sm[LDS_TOT];
    const int b = blockIdx.x, tid = threadIdx.x;
    const int l  = tid & 63;
    const int w  = __builtin_amdgcn_readfirstlane(tid >> 6);   // wave = head
    const int lc = l & 15, q4 = l >> 4;

    // ---- stage per-window scalars (barrier deferred: V pass touches only slice cols) ----
    if (tid < NTOK){
        float u  = u_temp[b*NTOK + tid];
        float sg = 1.f / (1.f + __expf(-u));
        sm[LDS_RT + tid] = 0.17677669529663687f / (0.1f + 4.f*sg);   // (1/sqrt32)/T
        float ub = u_bias[b*NTOK + tid];
        sm[LDS_UB + tid] = ub > 0.f ? ub : 0.f;
    }
    if (tid < 196) sm[LDS_GATE + tid] = gate[b*196 + tid];

    const unsigned short* qkh = (const unsigned short*)ws;
    const unsigned short* qkl = qkh + 49152;

    // ---- V pass first (no scalar deps), extract PV B-frags (bf16-hi) to regs ----
    qkv_pass(x, qkh, qkl, qkv_b, sm, b, w, lc, q4, 16, false);
    s8v Vb[2][2];
    #pragma unroll
    for (int t = 0; t < 2; ++t)
        #pragma unroll
        for (int kf = 0; kf < 2; ++kf)
            #pragma unroll
            for (int j = 0; j < 8; ++j){
                int key = kf*32 + q4*8 + j; if (key > 48) key = 48;
                Vb[t][kf][j] = (short)(__float_as_uint(sm[key*132 + w*32 + t*16 + lc]) >> 16);
            }

    __syncthreads();   // #1: scalars ready (RT needed by Q pass; also covers UB/GATE)

    // ---- Q pass (over V slice; Vb already in regs), extract S B-frags ----
    qkv_pass(x, qkh, qkl, qkv_b, sm, b, w, lc, q4, 0, true);
    s8v Qh[4], Ql[4];
    #pragma unroll
    for (int t = 0; t < 4; ++t){
        int row = 16*t + lc; if (row > 48) row = 48;
        const float* p = &sm[row*132 + w*32 + q4*8];
        float fv[8];
        float4 a0 = *(const float4*)p; float4 a1 = *(const float4*)(p + 4);
        fv[0]=a0.x; fv[1]=a0.y; fv[2]=a0.z; fv[3]=a0.w;
        fv[4]=a1.x; fv[5]=a1.y; fv[6]=a1.z; fv[7]=a1.w;
        split8t(fv, Qh[t], Ql[t]);
    }

    // ---- K pass (over Q slice; Q frags in regs), extract S A-frags ----
    qkv_pass(x, qkh, qkl, qkv_b, sm, b, w, lc, q4, 8, false);
    s8v Kh[4], Kl[4];
    #pragma unroll
    for (int t = 0; t < 4; ++t){
        int row = 16*t + lc; if (row > 48) row = 48;
        const float* p = &sm[row*132 + w*32 + q4*8];
        float fv[8];
        float4 a0 = *(const float4*)p; float4 a1 = *(const float4*)(p + 4);
        fv[0]=a0.x; fv[1]=a0.y; fv[2]=a0.z; fv[3]=a0.w;
        fv[4]=a1.x; fv[5]=a1.y; fv[6]=a1.z; fv[7]=a1.w;
        split8t(fv, Kh[t], Kl[t]);
    }

    // ---- S^T = K·Q^T, streamed per query-tile nt (S live = 16 regs, not 64) ----
    const float* biasT = (const float*)((const char*)ws + WS_BIAS_OFF);
    unsigned short* P = (unsigned short*)sm;   // bf16 P overlays slice (K dead)
    #pragma unroll
    for (int nt = 0; nt < 4; ++nt){
        int qy = nt*16 + lc;
        int qyc = qy > 48 ? 48 : qy;
        f4v S[4];
        #pragma unroll
        for (int mt = 0; mt < 4; ++mt){
            f4v a;
            #pragma unroll
            for (int r = 0; r < 4; ++r){
                int ky = mt*16 + q4*4 + r; if (ky > 48) ky = 48;
                a[r] = biasT[w*2401 + qyc*49 + ky] - sm[LDS_UB + ky];
            }
            a = MFMA(Kh[mt], Qh[nt], a);
            a = MFMA(Kh[mt], Ql[nt], a);
            a = MFMA(Kl[mt], Qh[nt], a);
            S[mt] = a;
        }
        #pragma unroll
        for (int r = 0; r < 4; ++r){
            int ky = 48 + q4*4 + r;
            if (ky >= NTOK) S[3][r] = -1e30f;
        }
        float mx = -3e38f;
        #pragma unroll
        for (int mt = 0; mt < 4; ++mt)
            #pragma unroll
            for (int r = 0; r < 4; ++r) mx = fmaxf(mx, S[mt][r]);
        mx = fmaxf(mx, __shfl_xor(mx, 16));
        mx = fmaxf(mx, __shfl_xor(mx, 32));
        float sum = 0.f;
        #pragma unroll
        for (int mt = 0; mt < 4; ++mt)
            #pragma unroll
            for (int r = 0; r < 4; ++r){
                float e = __expf(S[mt][r] - mx);
                S[mt][r] = e; sum += e;
            }
        sum += __shfl_xor(sum, 16);
        sum += __shfl_xor(sum, 32);
        float rs = 1.f / sum;
        if (qy < NTOK){
            #pragma unroll
            for (int mt = 0; mt < 4; ++mt)
                #pragma unroll
                for (int r = 0; r < 4; ++r){
                    int ky = mt*16 + q4*4 + r;
                    P[(qy*132 + w*32)*2 + (((ky>>3) ^ (qy&7)) << 3) + (ky&7)] = f2bf(S[mt][r] * rs);
                }
        }
    }

    // ---- PV (P frags from swizzled slice; V frags already in regs) ----
    s8v Pa[4][2];
    #pragma unroll
    for (int mt = 0; mt < 4; ++mt)
        #pragma unroll
        for (int kf = 0; kf < 2; ++kf){
            int qy = mt*16 + lc; if (qy > 48) qy = 48;
            int ch = (4*kf + q4) ^ (qy & 7);
            Pa[mt][kf] = *(const s8v*)(P + (qy*132 + w*32)*2 + ch*8);
        }
    f4v O[4][2];
    #pragma unroll
    for (int mt = 0; mt < 4; ++mt)
        #pragma unroll
        for (int t = 0; t < 2; ++t){
            f4v o = {0.f, 0.f, 0.f, 0.f};
            o = MFMA(Pa[mt][0], Vb[t][0], o);
            o = MFMA(Pa[mt][1], Vb[t][1], o);
            O[mt][t] = o;
        }

    // ---- gate + stage attn_out pre-split: hi u16[0..31] then lo u16[0..31] per row ----
    #pragma unroll
    for (int mt = 0; mt < 4; ++mt)
        #pragma unroll
        for (int t = 0; t < 2; ++t)
            #pragma unroll
            for (int r = 0; r < 4; ++r){
                int row = mt*16 + q4*4 + r;
                if (row < NTOK){
                    float vg = O[mt][t][r] * sm[LDS_GATE + w*49 + row];
                    unsigned u = __float_as_uint(vg);
                    float res = vg - __uint_as_float(u & 0xffff0000u);
                    char* bp = (char*)sm + (row*132 + w*32)*4;
                    ((unsigned short*)bp)[t*16 + lc]        = (unsigned short)(u >> 16);
                    ((unsigned short*)(bp + 64))[t*16 + lc] = (unsigned short)(__float_as_uint(res) >> 16);
                }
            }
    __syncthreads();   // #2: the single cross-wave handoff (all heads' attn_out -> proj)

    // ---- proj GEMM (split-bf16, 3 MFMAs); A-frags: head kf's block = cols 32*kf ----
    const unsigned short* ph = (const unsigned short*)((const char*)ws + 196608);
    const unsigned short* pl = (const unsigned short*)((const char*)ws + 229376);
    s8v Bh[2][4], Bl[2][4];
    #pragma unroll
    for (int t = 0; t < 2; ++t){
        int col = (2*w + t)*16 + lc;
        #pragma unroll
        for (int kf = 0; kf < 4; ++kf){
            int off = col*128 + kf*32 + q4*8;
            Bh[t][kf] = *(const s8v*)(ph + off);
            Bl[t][kf] = *(const s8v*)(pl + off);
        }
    }
    #pragma unroll
    for (int mt = 0; mt < 4; ++mt){
        int row = mt*16 + lc; if (row > 48) row = 48;
        s8v Ah[4], Al[4];
        #pragma unroll
        for (int kf = 0; kf < 4; ++kf){
            const char* bp = (const char*)sm + (row*132 + kf*32)*4;
            Ah[kf] = *(const s8v*)(bp + q4*16);
            Al[kf] = *(const s8v*)(bp + 64 + q4*16);
        }
        #pragma unroll
        for (int t = 0; t < 2; ++t){
            int col = (2*w + t)*16 + lc;
            float bia = proj_b[col];
            f4v acc = {bia, bia, bia, bia};
            #pragma unroll
            for (int kf = 0; kf < 4; ++kf){
                acc = MFMA(Ah[kf], Bh[t][kf], acc);
                acc = MFMA(Ah[kf], Bl[t][kf], acc);
                acc = MFMA(Al[kf], Bh[t][kf], acc);
            }
            #pragma unroll
            for (int r = 0; r < 4; ++r){
                int r2 = mt*16 + q4*4 + r;
                if (r2 < NTOK) out[((size_t)b*NTOK + r2)*128 + col] = acc[r];
            }
        }
    }
}

extern "C" void kernel_launch(void* const* d_in, const int* in_sizes, int n_in,
                              void* d_out, int out_size, void* d_ws, size_t ws_size,
                              hipStream_t stream) {
    const float* x  = (const float*)d_in[0];
    const float* ut = (const float*)d_in[1];
    const float* ub = (const float*)d_in[2];
    const float* tg = (const float*)d_in[3];
    const float* qw = (const float*)d_in[4];
    const float* qb = (const float*)d_in[5];
    const float* pw = (const float*)d_in[6];
    const float* pb = (const float*)d_in[7];
    const float* rt = (const float*)d_in[8];
    const int*   ri = (const int*)d_in[9];
    float* o = (float*)d_out;
    const int B = in_sizes[0] / (NTOK * 128);

    prep_kernel<<<294, 256, 0, stream>>>(qw, pw, rt, ri, d_ws);
    win_attn<<<B, 256, 0, stream>>>(x, ut, ub, tg, qb, pb, d_ws, o);
}

// Round 3
// 496.774 us; speedup vs baseline: 1.5175x; 1.5175x over previous
//
#include <hip/hip_runtime.h>

typedef short s8v __attribute__((ext_vector_type(8)));
typedef float f4v __attribute__((ext_vector_type(4)));

#define NTOK 49
// LDS float offsets
#define LDS_Q    0        // fp32 [49][132] q (wave w owns cols 32w..32w+31); P[w] overlays same cols
#define LDS_K    6468     // fp32 [49][132] k (per-wave cols); v[w] then attn_hi/lo[w] overlay same cols
#define LDS_RT   12936    // [49] 0.17678/T
#define LDS_UB   12985    // [49] relu(u_bias)
#define LDS_GATE 13034    // [4][49]
#define LDS_TOT  13230    // 52920 bytes -> 53248 granule; 3 blocks/CU (LDS cap == reg cap at 3 waves/EU)

// ws byte layout: qkv_hi u16[49152] @0 ; qkv_lo @98304 ; proj_hi u16[16384] @196608 ;
//                 proj_lo @229376 ; bias f32[4][49][49] @262144
#define WS_BIAS_OFF 262144

__device__ __forceinline__ unsigned short f2bf(float f){          // RNE
    unsigned x = __float_as_uint(f);
    x += 0x7fffu + ((x >> 16) & 1u);
    return (unsigned short)(x >> 16);
}
// truncation split: hi = top16(f), lo = top16(f - hi). err <= 2^-16 |f|
__device__ __forceinline__ void split8t(const float* f, s8v& hi, s8v& lo){
    #pragma unroll
    for (int j = 0; j < 8; ++j){
        unsigned u = __float_as_uint(f[j]);
        hi[j] = (short)(u >> 16);
        float r = f[j] - __uint_as_float(u & 0xffff0000u);
        lo[j] = (short)(__float_as_uint(r) >> 16);
    }
}

__global__ void prep_kernel(const float* __restrict__ qkv_w, const float* __restrict__ proj_w,
                            const float* __restrict__ rel_table, const int* __restrict__ rel_index,
                            void* __restrict__ ws){
    int i = blockIdx.x * 256 + threadIdx.x;
    unsigned short* qh = (unsigned short*)ws;
    unsigned short* ql = qh + 49152;
    unsigned short* ph = (unsigned short*)((char*)ws + 196608);
    unsigned short* pl = (unsigned short*)((char*)ws + 229376);
    float* biasT = (float*)((char*)ws + WS_BIAS_OFF);
    if (i < 49152){
        float v = qkv_w[i];
        unsigned u = __float_as_uint(v);
        qh[i] = (unsigned short)(u >> 16);
        ql[i] = (unsigned short)(__float_as_uint(v - __uint_as_float(u & 0xffff0000u)) >> 16);
    } else if (i < 65536){
        int j = i - 49152;
        float v = proj_w[j];
        unsigned u = __float_as_uint(v);
        ph[j] = (unsigned short)(u >> 16);
        pl[j] = (unsigned short)(__float_as_uint(v - __uint_as_float(u & 0xffff0000u)) >> 16);
    } else if (i < 75140){
        int j = i - 65536;
        int h = j / 2401, r = j % 2401;       // r = q*49 + k
        biasT[h*2401 + r] = rel_table[rel_index[r]*4 + h];
    }
}

#define MFMA(a,b,c) __builtin_amdgcn_mfma_f32_16x16x32_bf16((a),(b),(c),0,0,0)

__global__ __launch_bounds__(256, 3)
void win_attn(const float* __restrict__ x, const float* __restrict__ u_temp,
              const float* __restrict__ u_bias, const float* __restrict__ gate,
              const float* __restrict__ qkv_b, const float* __restrict__ proj_b,
              const void* __restrict__ ws, float* __restrict__ out)
{
    __shared__ float sm[LDS_TOT];
    const int b = blockIdx.x, tid = threadIdx.x;
    const int l  = tid & 63;
    const int w  = __builtin_amdgcn_readfirstlane(tid >> 6);   // wave = head
    const int lc = l & 15, q4 = l >> 4;

    // ---- stage per-window scalars ----
    if (tid < NTOK){
        float u  = u_temp[b*NTOK + tid];
        float sg = 1.f / (1.f + __expf(-u));
        sm[LDS_RT + tid] = 0.17677669529663687f / (0.1f + 4.f*sg);   // (1/sqrt32)/T
        float ub = u_bias[b*NTOK + tid];
        sm[LDS_UB + tid] = ub > 0.f ? ub : 0.f;
    }
    if (tid < 196) sm[LDS_GATE + tid] = gate[b*196 + tid];
    __syncthreads();   // #1: the only pre-proj barrier

    const unsigned short* qkh = (const unsigned short*)ws;
    const unsigned short* qkl = qkh + 49152;

    // ---- phase A: QKV GEMM (split-bf16, 3 MFMAs). Wave w computes head w's q,k,v only. ----
    f4v vhold[2][4];   // v D-tiles [t][mt] held in regs
    #pragma unroll
    for (int mp = 0; mp < 2; ++mp){
        s8v ah[2][4], al[2][4];
        #pragma unroll
        for (int m2 = 0; m2 < 2; ++m2){
            int row = (mp*2 + m2)*16 + lc; if (row > 48) row = 48;
            const float* xp = x + ((size_t)b*NTOK + row)*128 + q4*8;
            #pragma unroll
            for (int kf = 0; kf < 4; ++kf){
                float xv[8];
                float4 t0 = *(const float4*)(xp + kf*32);
                float4 t1 = *(const float4*)(xp + kf*32 + 4);
                xv[0]=t0.x; xv[1]=t0.y; xv[2]=t0.z; xv[3]=t0.w;
                xv[4]=t1.x; xv[5]=t1.y; xv[6]=t1.z; xv[7]=t1.w;
                split8t(xv, ah[m2][kf], al[m2][kf]);
            }
        }
        #pragma unroll
        for (int g = 0; g < 3; ++g){
            #pragma unroll
            for (int t = 0; t < 2; ++t){
                int nt  = (g==0 ? 2*w : (g==1 ? 8+2*w : 16+2*w)) + t;
                int col = nt*16 + lc;
                s8v bh[4], bl[4];
                #pragma unroll
                for (int kf = 0; kf < 4; ++kf){
                    int off = col*128 + kf*32 + q4*8;
                    bh[kf] = *(const s8v*)(qkh + off);
                    bl[kf] = *(const s8v*)(qkl + off);
                }
                float bia = qkv_b[col];
                #pragma unroll
                for (int m2 = 0; m2 < 2; ++m2){
                    f4v acc = {bia, bia, bia, bia};
                    #pragma unroll
                    for (int kf = 0; kf < 4; ++kf){
                        acc = MFMA(ah[m2][kf], bh[kf], acc);
                        acc = MFMA(ah[m2][kf], bl[kf], acc);
                        acc = MFMA(al[m2][kf], bh[kf], acc);
                    }
                    int mt = mp*2 + m2;
                    if (g == 2){
                        vhold[t][mt] = acc;
                    } else {
                        #pragma unroll
                        for (int r = 0; r < 4; ++r){
                            int row = mt*16 + q4*4 + r;
                            if (row < NTOK){
                                if (g == 0) sm[LDS_Q + row*132 + col] = acc[r] * sm[LDS_RT + row];
                                else        sm[LDS_K + row*132 + (col - 128)] = acc[r];
                            }
                        }
                    }
                }
            }
        }
    }
    // no barrier: wave w reads only its own q/k columns below

    // ---- phase B: extract K/Q split-bf16 frags from own LDS cols ----
    s8v Kh[4], Kl[4], Qh[4], Ql[4];
    #pragma unroll
    for (int t = 0; t < 4; ++t){
        int row = 16*t + lc; if (row > 48) row = 48;
        float fv[8];
        {
            const float* p = &sm[LDS_K + row*132 + w*32 + q4*8];
            float4 a0 = *(const float4*)p; float4 a1 = *(const float4*)(p + 4);
            fv[0]=a0.x; fv[1]=a0.y; fv[2]=a0.z; fv[3]=a0.w;
            fv[4]=a1.x; fv[5]=a1.y; fv[6]=a1.z; fv[7]=a1.w;
            split8t(fv, Kh[t], Kl[t]);
        }
        {
            const float* p = &sm[LDS_Q + row*132 + w*32 + q4*8];
            float4 a0 = *(const float4*)p; float4 a1 = *(const float4*)(p + 4);
            fv[0]=a0.x; fv[1]=a0.y; fv[2]=a0.z; fv[3]=a0.w;
            fv[4]=a1.x; fv[5]=a1.y; fv[6]=a1.z; fv[7]=a1.w;
            split8t(fv, Qh[t], Ql[t]);
        }
    }

    // ---- S^T = K·Q^T, streamed per query-tile nt (S live = 16 regs, not 64) ----
    const float* biasT = (const float*)((const char*)ws + WS_BIAS_OFF);
    unsigned short* P = (unsigned short*)sm;   // bf16 P overlays LDS_Q (Q frags already in regs)
    #pragma unroll
    for (int nt = 0; nt < 4; ++nt){
        int qy = nt*16 + lc;
        int qyc = qy > 48 ? 48 : qy;
        f4v S[4];
        #pragma unroll
        for (int mt = 0; mt < 4; ++mt){
            f4v a;
            #pragma unroll
            for (int r = 0; r < 4; ++r){
                int ky = mt*16 + q4*4 + r; if (ky > 48) ky = 48;
                a[r] = biasT[w*2401 + qyc*49 + ky] - sm[LDS_UB + ky];
            }
            a = MFMA(Kh[mt], Qh[nt], a);
            a = MFMA(Kh[mt], Ql[nt], a);
            a = MFMA(Kl[mt], Qh[nt], a);
            S[mt] = a;
        }
        #pragma unroll
        for (int r = 0; r < 4; ++r){
            int ky = 48 + q4*4 + r;
            if (ky >= NTOK) S[3][r] = -1e30f;
        }
        float mx = -3e38f;
        #pragma unroll
        for (int mt = 0; mt < 4; ++mt)
            #pragma unroll
            for (int r = 0; r < 4; ++r) mx = fmaxf(mx, S[mt][r]);
        mx = fmaxf(mx, __shfl_xor(mx, 16));
        mx = fmaxf(mx, __shfl_xor(mx, 32));
        float sum = 0.f;
        #pragma unroll
        for (int mt = 0; mt < 4; ++mt)
            #pragma unroll
            for (int r = 0; r < 4; ++r){
                float e = __expf(S[mt][r] - mx);
                S[mt][r] = e; sum += e;
            }
        sum += __shfl_xor(sum, 16);
        sum += __shfl_xor(sum, 32);
        float rs = 1.f / sum;
        // ---- write P (bf16, q-slot cols 32w as u16 pairs, XOR-swizzled) ----
        if (qy < NTOK){
            #pragma unroll
            for (int mt = 0; mt < 4; ++mt)
                #pragma unroll
                for (int r = 0; r < 4; ++r){
                    int ky = mt*16 + q4*4 + r;
                    P[(qy*132 + w*32)*2 + (((ky>>3) ^ (qy&7)) << 3) + (ky&7)] = f2bf(S[mt][r] * rs);
                }
        }
    }
    // no barrier: overlays below touch only wave w's own columns

    // ---- stage v (fp32, k-slot cols 32w; k frags already in regs) ----
    #pragma unroll
    for (int t = 0; t < 2; ++t)
        #pragma unroll
        for (int mt = 0; mt < 4; ++mt)
            #pragma unroll
            for (int r = 0; r < 4; ++r){
                int row = mt*16 + q4*4 + r;
                if (row < NTOK) sm[LDS_K + row*132 + w*32 + t*16 + lc] = vhold[t][mt][r];
            }

    // ---- PV (same-wave LDS round trip) ----
    s8v Pa[4][2];
    #pragma unroll
    for (int mt = 0; mt < 4; ++mt)
        #pragma unroll
        for (int kf = 0; kf < 2; ++kf){
            int qy = mt*16 + lc; if (qy > 48) qy = 48;
            int ch = (4*kf + q4) ^ (qy & 7);
            Pa[mt][kf] = *(const s8v*)(P + (qy*132 + w*32)*2 + ch*8);
        }
    s8v Vb[2][2];
    #pragma unroll
    for (int t = 0; t < 2; ++t)
        #pragma unroll
        for (int kf = 0; kf < 2; ++kf){
            #pragma unroll
            for (int j = 0; j < 8; ++j){
                int key = kf*32 + q4*8 + j; if (key > 48) key = 48;
                Vb[t][kf][j] = (short)(__float_as_uint(sm[LDS_K + key*132 + w*32 + t*16 + lc]) >> 16);
            }
        }
    f4v O[4][2];
    #pragma unroll
    for (int mt = 0; mt < 4; ++mt)
        #pragma unroll
        for (int t = 0; t < 2; ++t){
            f4v o = {0.f, 0.f, 0.f, 0.f};
            o = MFMA(Pa[mt][0], Vb[t][0], o);
            o = MFMA(Pa[mt][1], Vb[t][1], o);
            O[mt][t] = o;
        }
    // no barrier: attn write below goes to wave w's own k-slot columns (own v, now dead)

    // ---- gate + stage attn_out pre-split: hi u16[0..31] then lo u16[0..31] per row, in k-cols 32w ----
    #pragma unroll
    for (int mt = 0; mt < 4; ++mt)
        #pragma unroll
        for (int t = 0; t < 2; ++t)
            #pragma unroll
            for (int r = 0; r < 4; ++r){
                int row = mt*16 + q4*4 + r;
                if (row < NTOK){
                    float vg = O[mt][t][r] * sm[LDS_GATE + w*49 + row];
                    unsigned u = __float_as_uint(vg);
                    float res = vg - __uint_as_float(u & 0xffff0000u);
                    char* bp = (char*)sm + (LDS_K + row*132 + w*32)*4;
                    ((unsigned short*)bp)[t*16 + lc]        = (unsigned short)(u >> 16);
                    ((unsigned short*)(bp + 64))[t*16 + lc] = (unsigned short)(__float_as_uint(res) >> 16);
                }
            }
    __syncthreads();   // #2: the single cross-wave handoff (all heads' attn_out -> proj)

    // ---- proj GEMM (split-bf16, 3 MFMAs); A-frags: head kf's block = k-cols 32*kf ----
    const unsigned short* ph = (const unsigned short*)((const char*)ws + 196608);
    const unsigned short* pl = (const unsigned short*)((const char*)ws + 229376);
    s8v Bh[2][4], Bl[2][4];
    #pragma unroll
    for (int t = 0; t < 2; ++t){
        int col = (2*w + t)*16 + lc;
        #pragma unroll
        for (int kf = 0; kf < 4; ++kf){
            int off = col*128 + kf*32 + q4*8;
            Bh[t][kf] = *(const s8v*)(ph + off);
            Bl[t][kf] = *(const s8v*)(pl + off);
        }
    }
    #pragma unroll
    for (int mt = 0; mt < 4; ++mt){
        int row = mt*16 + lc; if (row > 48) row = 48;
        s8v Ah[4], Al[4];
        #pragma unroll
        for (int kf = 0; kf < 4; ++kf){
            const char* bp = (const char*)sm + (LDS_K + row*132 + kf*32)*4;
            Ah[kf] = *(const s8v*)(bp + q4*16);
            Al[kf] = *(const s8v*)(bp + 64 + q4*16);
        }
        #pragma unroll
        for (int t = 0; t < 2; ++t){
            int col = (2*w + t)*16 + lc;
            float bia = proj_b[col];
            f4v acc = {bia, bia, bia, bia};
            #pragma unroll
            for (int kf = 0; kf < 4; ++kf){
                acc = MFMA(Ah[kf], Bh[t][kf], acc);
                acc = MFMA(Ah[kf], Bl[t][kf], acc);
                acc = MFMA(Al[kf], Bh[t][kf], acc);
            }
            #pragma unroll
            for (int r = 0; r < 4; ++r){
                int r2 = mt*16 + q4*4 + r;
                if (r2 < NTOK) out[((size_t)b*NTOK + r2)*128 + col] = acc[r];
            }
        }
    }
}

extern "C" void kernel_launch(void* const* d_in, const int* in_sizes, int n_in,
                              void* d_out, int out_size, void* d_ws, size_t ws_size,
                              hipStream_t stream) {
    const float* x  = (const float*)d_in[0];
    const float* ut = (const float*)d_in[1];
    const float* ub = (const float*)d_in[2];
    const float* tg = (const float*)d_in[3];
    const float* qw = (const float*)d_in[4];
    const float* qb = (const float*)d_in[5];
    const float* pw = (const float*)d_in[6];
    const float* pb = (const float*)d_in[7];
    const float* rt = (const float*)d_in[8];
    const int*   ri = (const int*)d_in[9];
    float* o = (float*)d_out;
    const int B = in_sizes[0] / (NTOK * 128);

    prep_kernel<<<294, 256, 0, stream>>>(qw, pw, rt, ri, d_ws);
    win_attn<<<B, 256, 0, stream>>>(x, ut, ub, tg, qb, pb, d_ws, o);
}

// Round 5
// 493.759 us; speedup vs baseline: 1.5268x; 1.0061x over previous
//
#include <hip/hip_runtime.h>

typedef short s8v __attribute__((ext_vector_type(8)));
typedef float f4v __attribute__((ext_vector_type(4)));

#define NTOK 49
// LDS float offsets
#define LDS_Q    0        // fp32 [49][132] q (wave w owns cols 32w..32w+31); P[w] overlays same cols
#define LDS_K    6468     // fp32 [49][132] k (per-wave cols); v-u16[w] then attn_hi/lo[w] overlay same cols
#define LDS_RT   12936    // [49] 0.17678/T
#define LDS_UB   12985    // [49] relu(u_bias)
#define LDS_GATE 13034    // [4][49]
#define LDS_TOT  13230    // 52920 bytes -> 53248 granule; 3 blocks/CU (LDS cap == reg cap at 3 waves/EU)

// ws byte layout: qkv_hi u16[49152] @0 ; qkv_lo @98304 ; proj_hi u16[16384] @196608 ;
//                 proj_lo @229376 ; bias f32[4][49][49] @262144
#define WS_BIAS_OFF 262144

__device__ __forceinline__ unsigned short f2bf(float f){          // RNE
    unsigned x = __float_as_uint(f);
    x += 0x7fffu + ((x >> 16) & 1u);
    return (unsigned short)(x >> 16);
}
// truncation split: hi = top16(f), lo = top16(f - hi). err <= 2^-16 |f|
__device__ __forceinline__ void split8t(const float* f, s8v& hi, s8v& lo){
    #pragma unroll
    for (int j = 0; j < 8; ++j){
        unsigned u = __float_as_uint(f[j]);
        hi[j] = (short)(u >> 16);
        float r = f[j] - __uint_as_float(u & 0xffff0000u);
        lo[j] = (short)(__float_as_uint(r) >> 16);
    }
}

__global__ void prep_kernel(const float* __restrict__ qkv_w, const float* __restrict__ proj_w,
                            const float* __restrict__ rel_table, const int* __restrict__ rel_index,
                            void* __restrict__ ws){
    int i = blockIdx.x * 256 + threadIdx.x;
    unsigned short* qh = (unsigned short*)ws;
    unsigned short* ql = qh + 49152;
    unsigned short* ph = (unsigned short*)((char*)ws + 196608);
    unsigned short* pl = (unsigned short*)((char*)ws + 229376);
    float* biasT = (float*)((char*)ws + WS_BIAS_OFF);
    if (i < 49152){
        float v = qkv_w[i];
        unsigned u = __float_as_uint(v);
        qh[i] = (unsigned short)(u >> 16);
        ql[i] = (unsigned short)(__float_as_uint(v - __uint_as_float(u & 0xffff0000u)) >> 16);
    } else if (i < 65536){
        int j = i - 49152;
        float v = proj_w[j];
        unsigned u = __float_as_uint(v);
        ph[j] = (unsigned short)(u >> 16);
        pl[j] = (unsigned short)(__float_as_uint(v - __uint_as_float(u & 0xffff0000u)) >> 16);
    } else if (i < 75140){
        int j = i - 65536;
        int h = j / 2401, r = j % 2401;       // r = q*49 + k
        biasT[h*2401 + r] = rel_table[rel_index[r]*4 + h];
    }
}

#define MFMA(a,b,c) __builtin_amdgcn_mfma_f32_16x16x32_bf16((a),(b),(c),0,0,0)

__global__ __launch_bounds__(256, 3)
void win_attn(const float* __restrict__ x, const float* __restrict__ u_temp,
              const float* __restrict__ u_bias, const float* __restrict__ gate,
              const float* __restrict__ qkv_b, const float* __restrict__ proj_b,
              const void* __restrict__ ws, float* __restrict__ out)
{
    __shared__ float sm[LDS_TOT];
    const int b = blockIdx.x, tid = threadIdx.x;
    const int l  = tid & 63;
    const int w  = __builtin_amdgcn_readfirstlane(tid >> 6);   // wave = head
    const int lc = l & 15, q4 = l >> 4;

    // ---- stage per-window scalars ----
    if (tid < NTOK){
        float u  = u_temp[b*NTOK + tid];
        float sg = 1.f / (1.f + __expf(-u));
        sm[LDS_RT + tid] = 0.17677669529663687f / (0.1f + 4.f*sg);   // (1/sqrt32)/T
        float ub = u_bias[b*NTOK + tid];
        sm[LDS_UB + tid] = ub > 0.f ? ub : 0.f;
    }
    if (tid < 196) sm[LDS_GATE + tid] = gate[b*196 + tid];
    __syncthreads();   // #1: the only pre-proj barrier

    const unsigned short* qkh = (const unsigned short*)ws;
    const unsigned short* qkl = qkh + 49152;

    // ---- phase A: QKV GEMM (split-bf16, 3 MFMAs). Wave w computes head w's q,k,v only. ----
    // v held packed bf16-hi (truncation identical to old read-side >>16): 16 regs not 32.
    unsigned vpk[2][4][2];
    #pragma unroll
    for (int mp = 0; mp < 2; ++mp){
        s8v ah[2][4], al[2][4];
        #pragma unroll
        for (int m2 = 0; m2 < 2; ++m2){
            int row = (mp*2 + m2)*16 + lc; if (row > 48) row = 48;
            const float* xp = x + ((size_t)b*NTOK + row)*128 + q4*8;
            #pragma unroll
            for (int kf = 0; kf < 4; ++kf){
                float xv[8];
                float4 t0 = *(const float4*)(xp + kf*32);
                float4 t1 = *(const float4*)(xp + kf*32 + 4);
                xv[0]=t0.x; xv[1]=t0.y; xv[2]=t0.z; xv[3]=t0.w;
                xv[4]=t1.x; xv[5]=t1.y; xv[6]=t1.z; xv[7]=t1.w;
                split8t(xv, ah[m2][kf], al[m2][kf]);
            }
        }
        #pragma unroll
        for (int g = 0; g < 3; ++g){
            #pragma unroll
            for (int t = 0; t < 2; ++t){
                int nt  = (g==0 ? 2*w : (g==1 ? 8+2*w : 16+2*w)) + t;
                int col = nt*16 + lc;
                float bia = qkv_b[col];
                f4v acc0 = {bia, bia, bia, bia};
                f4v acc1 = {bia, bia, bia, bia};
                // B-frags loaded per-kf (8 regs live, not 32)
                #pragma unroll
                for (int kf = 0; kf < 4; ++kf){
                    int off = col*128 + kf*32 + q4*8;
                    s8v bh = *(const s8v*)(qkh + off);
                    s8v bl = *(const s8v*)(qkl + off);
                    acc0 = MFMA(ah[0][kf], bh, acc0);
                    acc0 = MFMA(ah[0][kf], bl, acc0);
                    acc0 = MFMA(al[0][kf], bh, acc0);
                    acc1 = MFMA(ah[1][kf], bh, acc1);
                    acc1 = MFMA(ah[1][kf], bl, acc1);
                    acc1 = MFMA(al[1][kf], bh, acc1);
                }
                if (g == 2){
                    unsigned u0 = __float_as_uint(acc0[0]), u1 = __float_as_uint(acc0[1]);
                    unsigned u2 = __float_as_uint(acc0[2]), u3 = __float_as_uint(acc0[3]);
                    vpk[t][mp*2+0][0] = (u0 >> 16) | (u1 & 0xffff0000u);
                    vpk[t][mp*2+0][1] = (u2 >> 16) | (u3 & 0xffff0000u);
                    u0 = __float_as_uint(acc1[0]); u1 = __float_as_uint(acc1[1]);
                    u2 = __float_as_uint(acc1[2]); u3 = __float_as_uint(acc1[3]);
                    vpk[t][mp*2+1][0] = (u0 >> 16) | (u1 & 0xffff0000u);
                    vpk[t][mp*2+1][1] = (u2 >> 16) | (u3 & 0xffff0000u);
                } else {
                    #pragma unroll
                    for (int r = 0; r < 4; ++r){
                        int row0 = (mp*2 + 0)*16 + q4*4 + r;
                        if (row0 < NTOK){
                            if (g == 0) sm[LDS_Q + row0*132 + col] = acc0[r] * sm[LDS_RT + row0];
                            else        sm[LDS_K + row0*132 + (col - 128)] = acc0[r];
                        }
                        int row1 = (mp*2 + 1)*16 + q4*4 + r;
                        if (row1 < NTOK){
                            if (g == 0) sm[LDS_Q + row1*132 + col] = acc1[r] * sm[LDS_RT + row1];
                            else        sm[LDS_K + row1*132 + (col - 128)] = acc1[r];
                        }
                    }
                }
            }
        }
    }
    // no barrier: wave w reads only its own q/k columns below

    // ---- phase B: extract K split-bf16 frags from own LDS cols (K stays resident; Q streamed) ----
    s8v Kh[4], Kl[4];
    #pragma unroll
    for (int t = 0; t < 4; ++t){
        int row = 16*t + lc; if (row > 48) row = 48;
        float fv[8];
        const float* p = &sm[LDS_K + row*132 + w*32 + q4*8];
        float4 a0 = *(const float4*)p; float4 a1 = *(const float4*)(p + 4);
        fv[0]=a0.x; fv[1]=a0.y; fv[2]=a0.z; fv[3]=a0.w;
        fv[4]=a1.x; fv[5]=a1.y; fv[6]=a1.z; fv[7]=a1.w;
        split8t(fv, Kh[t], Kl[t]);
    }

    // ---- S^T = K·Q^T, streamed per query-tile nt; Q frag read+split inside loop ----
    const float* biasT = (const float*)((const char*)ws + WS_BIAS_OFF);
    unsigned short* P = (unsigned short*)sm;   // bf16 P overlays LDS_Q rows of already-consumed nt
    #pragma unroll
    for (int nt = 0; nt < 4; ++nt){
        // Q frag for this nt only (16 regs transient; P writes of prior nt are row-disjoint)
        s8v Qh, Ql;
        {
            int row = 16*nt + lc; if (row > 48) row = 48;
            float fv[8];
            const float* p = &sm[LDS_Q + row*132 + w*32 + q4*8];
            float4 a0 = *(const float4*)p; float4 a1 = *(const float4*)(p + 4);
            fv[0]=a0.x; fv[1]=a0.y; fv[2]=a0.z; fv[3]=a0.w;
            fv[4]=a1.x; fv[5]=a1.y; fv[6]=a1.z; fv[7]=a1.w;
            split8t(fv, Qh, Ql);
        }
        int qy = nt*16 + lc;
        int qyc = qy > 48 ? 48 : qy;
        f4v S[4];
        #pragma unroll
        for (int mt = 0; mt < 4; ++mt){
            f4v a;
            #pragma unroll
            for (int r = 0; r < 4; ++r){
                int ky = mt*16 + q4*4 + r; if (ky > 48) ky = 48;
                a[r] = biasT[w*2401 + qyc*49 + ky] - sm[LDS_UB + ky];
            }
            a = MFMA(Kh[mt], Qh, a);
            a = MFMA(Kh[mt], Ql, a);
            a = MFMA(Kl[mt], Qh, a);
            S[mt] = a;
        }
        #pragma unroll
        for (int r = 0; r < 4; ++r){
            int ky = 48 + q4*4 + r;
            if (ky >= NTOK) S[3][r] = -1e30f;
        }
        float mx = -3e38f;
        #pragma unroll
        for (int mt = 0; mt < 4; ++mt)
            #pragma unroll
            for (int r = 0; r < 4; ++r) mx = fmaxf(mx, S[mt][r]);
        mx = fmaxf(mx, __shfl_xor(mx, 16));
        mx = fmaxf(mx, __shfl_xor(mx, 32));
        float sum = 0.f;
        #pragma unroll
        for (int mt = 0; mt < 4; ++mt)
            #pragma unroll
            for (int r = 0; r < 4; ++r){
                float e = __expf(S[mt][r] - mx);
                S[mt][r] = e; sum += e;
            }
        sum += __shfl_xor(sum, 16);
        sum += __shfl_xor(sum, 32);
        float rs = 1.f / sum;
        // ---- write P (bf16, q-slot cols 32w as u16 pairs, XOR-swizzled) ----
        if (qy < NTOK){
            #pragma unroll
            for (int mt = 0; mt < 4; ++mt)
                #pragma unroll
                for (int r = 0; r < 4; ++r){
                    int ky = mt*16 + q4*4 + r;
                    P[(qy*132 + w*32)*2 + (((ky>>3) ^ (qy&7)) << 3) + (ky&7)] = f2bf(S[mt][r] * rs);
                }
        }
    }
    // no barrier: overlays below touch only wave w's own columns

    // ---- stage v (bf16-hi u16, k-slot cols 32w; k frags already in regs) ----
    unsigned short* vU = (unsigned short*)sm;
    #pragma unroll
    for (int t = 0; t < 2; ++t)
        #pragma unroll
        for (int mt = 0; mt < 4; ++mt)
            #pragma unroll
            for (int r = 0; r < 4; ++r){
                int row = mt*16 + q4*4 + r;
                if (row < NTOK){
                    unsigned pk = vpk[t][mt][r >> 1];
                    unsigned short hv = (unsigned short)((r & 1) ? (pk >> 16) : (pk & 0xffffu));
                    vU[(LDS_K + row*132 + w*32)*2 + t*16 + lc] = hv;
                }
            }

    // ---- PV (same-wave LDS round trip) ----
    s8v Pa[4][2];
    #pragma unroll
    for (int mt = 0; mt < 4; ++mt)
        #pragma unroll
        for (int kf = 0; kf < 2; ++kf){
            int qy = mt*16 + lc; if (qy > 48) qy = 48;
            int ch = (4*kf + q4) ^ (qy & 7);
            Pa[mt][kf] = *(const s8v*)(P + (qy*132 + w*32)*2 + ch*8);
        }
    s8v Vb[2][2];
    const unsigned short* vRd = (const unsigned short*)sm;
    #pragma unroll
    for (int t = 0; t < 2; ++t)
        #pragma unroll
        for (int kf = 0; kf < 2; ++kf){
            #pragma unroll
            for (int j = 0; j < 8; ++j){
                int key = kf*32 + q4*8 + j; if (key > 48) key = 48;
                Vb[t][kf][j] = (short)vRd[(LDS_K + key*132 + w*32)*2 + t*16 + lc];
            }
        }
    f4v O[4][2];
    #pragma unroll
    for (int mt = 0; mt < 4; ++mt)
        #pragma unroll
        for (int t = 0; t < 2; ++t){
            f4v o = {0.f, 0.f, 0.f, 0.f};
            o = MFMA(Pa[mt][0], Vb[t][0], o);
            o = MFMA(Pa[mt][1], Vb[t][1], o);
            O[mt][t] = o;
        }
    // no barrier: attn write below goes to wave w's own k-slot columns (own v, now dead)

    // ---- gate + stage attn_out pre-split: hi u16[0..31] then lo u16[0..31] per row, in k-cols 32w ----
    #pragma unroll
    for (int mt = 0; mt < 4; ++mt)
        #pragma unroll
        for (int t = 0; t < 2; ++t)
            #pragma unroll
            for (int r = 0; r < 4; ++r){
                int row = mt*16 + q4*4 + r;
                if (row < NTOK){
                    float vg = O[mt][t][r] * sm[LDS_GATE + w*49 + row];
                    unsigned u = __float_as_uint(vg);
                    float res = vg - __uint_as_float(u & 0xffff0000u);
                    char* bp = (char*)sm + (LDS_K + row*132 + w*32)*4;
                    ((unsigned short*)bp)[t*16 + lc]        = (unsigned short)(u >> 16);
                    ((unsigned short*)(bp + 64))[t*16 + lc] = (unsigned short)(__float_as_uint(res) >> 16);
                }
            }
    __syncthreads();   // #2: the single cross-wave handoff (all heads' attn_out -> proj)

    // ---- proj GEMM (split-bf16, 3 MFMAs); A-frags: head kf's block = k-cols 32*kf ----
    const unsigned short* ph = (const unsigned short*)((const char*)ws + 196608);
    const unsigned short* pl = (const unsigned short*)((const char*)ws + 229376);
    s8v Bh[2][4], Bl[2][4];
    #pragma unroll
    for (int t = 0; t < 2; ++t){
        int col = (2*w + t)*16 + lc;
        #pragma unroll
        for (int kf = 0; kf < 4; ++kf){
            int off = col*128 + kf*32 + q4*8;
            Bh[t][kf] = *(const s8v*)(ph + off);
            Bl[t][kf] = *(const s8v*)(pl + off);
        }
    }
    #pragma unroll
    for (int mt = 0; mt < 4; ++mt){
        int row = mt*16 + lc; if (row > 48) row = 48;
        s8v Ah[4], Al[4];
        #pragma unroll
        for (int kf = 0; kf < 4; ++kf){
            const char* bp = (const char*)sm + (LDS_K + row*132 + kf*32)*4;
            Ah[kf] = *(const s8v*)(bp + q4*16);
            Al[kf] = *(const s8v*)(bp + 64 + q4*16);
        }
        #pragma unroll
        for (int t = 0; t < 2; ++t){
            int col = (2*w + t)*16 + lc;
            float bia = proj_b[col];
            f4v acc = {bia, bia, bia, bia};
            #pragma unroll
            for (int kf = 0; kf < 4; ++kf){
                acc = MFMA(Ah[kf], Bh[t][kf], acc);
                acc = MFMA(Ah[kf], Bl[t][kf], acc);
                acc = MFMA(Al[kf], Bh[t][kf], acc);
            }
            #pragma unroll
            for (int r = 0; r < 4; ++r){
                int r2 = mt*16 + q4*4 + r;
                if (r2 < NTOK) out[((size_t)b*NTOK + r2)*128 + col] = acc[r];
            }
        }
    }
}

extern "C" void kernel_launch(void* const* d_in, const int* in_sizes, int n_in,
                              void* d_out, int out_size, void* d_ws, size_t ws_size,
                              hipStream_t stream) {
    const float* x  = (const float*)d_in[0];
    const float* ut = (const float*)d_in[1];
    const float* ub = (const float*)d_in[2];
    const float* tg = (const float*)d_in[3];
    const float* qw = (const float*)d_in[4];
    const float* qb = (const float*)d_in[5];
    const float* pw = (const float*)d_in[6];
    const float* pb = (const float*)d_in[7];
    const float* rt = (const float*)d_in[8];
    const int*   ri = (const int*)d_in[9];
    float* o = (float*)d_out;
    const int B = in_sizes[0] / (NTOK * 128);

    prep_kernel<<<294, 256, 0, stream>>>(qw, pw, rt, ri, d_ws);
    win_attn<<<B, 256, 0, stream>>>(x, ut, ub, tg, qb, pb, d_ws, o);
}

// Round 6
// 439.663 us; speedup vs baseline: 1.7146x; 1.1230x over previous
//
#include <hip/hip_runtime.h>

typedef short s8v __attribute__((ext_vector_type(8)));
typedef float f4v __attribute__((ext_vector_type(4)));

#define NTOK 49
// LDS float offsets
#define LDS_Q    0        // fp32 [49][132] q (wave w owns cols 32w..32w+31); P[w] overlays same cols
#define LDS_K    6468     // fp32 [49][132] k (per-wave cols); v[w] then attn_hi/lo[w] overlay same cols
#define LDS_RT   12936    // [49] 0.17678/T
#define LDS_UB   12985    // [49] relu(u_bias)
#define LDS_GATE 13034    // [4][49]
#define LDS_TOT  13230    // 52920 bytes -> 53248 granule

// ws byte layout: qkv_hi u16[49152] @0 ; qkv_lo @98304 ; proj_hi u16[16384] @196608 ;
//                 proj_lo @229376 ; bias f32[4][49][49] @262144  (K-MAJOR: [h][ky*49+qy])
#define WS_BIAS_OFF 262144

__device__ __forceinline__ unsigned short f2bf(float f){          // RNE
    unsigned x = __float_as_uint(f);
    x += 0x7fffu + ((x >> 16) & 1u);
    return (unsigned short)(x >> 16);
}
// truncation split: hi = top16(f), lo = top16(f - hi). err <= 2^-16 |f|
__device__ __forceinline__ void split8t(const float* f, s8v& hi, s8v& lo){
    #pragma unroll
    for (int j = 0; j < 8; ++j){
        unsigned u = __float_as_uint(f[j]);
        hi[j] = (short)(u >> 16);
        float r = f[j] - __uint_as_float(u & 0xffff0000u);
        lo[j] = (short)(__float_as_uint(r) >> 16);
    }
}

__global__ void prep_kernel(const float* __restrict__ qkv_w, const float* __restrict__ proj_w,
                            const float* __restrict__ rel_table, const int* __restrict__ rel_index,
                            void* __restrict__ ws){
    int i = blockIdx.x * 256 + threadIdx.x;
    unsigned short* qh = (unsigned short*)ws;
    unsigned short* ql = qh + 49152;
    unsigned short* ph = (unsigned short*)((char*)ws + 196608);
    unsigned short* pl = (unsigned short*)((char*)ws + 229376);
    float* biasT = (float*)((char*)ws + WS_BIAS_OFF);
    if (i < 49152){
        float v = qkv_w[i];
        unsigned u = __float_as_uint(v);
        qh[i] = (unsigned short)(u >> 16);
        ql[i] = (unsigned short)(__float_as_uint(v - __uint_as_float(u & 0xffff0000u)) >> 16);
    } else if (i < 65536){
        int j = i - 49152;
        float v = proj_w[j];
        unsigned u = __float_as_uint(v);
        ph[j] = (unsigned short)(u >> 16);
        pl[j] = (unsigned short)(__float_as_uint(v - __uint_as_float(u & 0xffff0000u)) >> 16);
    } else if (i < 75140){
        int j = i - 65536;
        int h = j / 2401, r = j % 2401;       // r = q*49 + k
        // K-MAJOR store: bias[h][k*49 + q]  (coalesced lane-contiguous q reads in S-phase)
        biasT[h*2401 + (r % 49)*49 + (r / 49)] = rel_table[rel_index[r]*4 + h];
    }
}

#define MFMA(a,b,c) __builtin_amdgcn_mfma_f32_16x16x32_bf16((a),(b),(c),0,0,0)

__global__ __launch_bounds__(256, 2)
void win_attn(const float* __restrict__ x, const float* __restrict__ u_temp,
              const float* __restrict__ u_bias, const float* __restrict__ gate,
              const float* __restrict__ qkv_b, const float* __restrict__ proj_b,
              const void* __restrict__ ws, float* __restrict__ out)
{
    __shared__ float sm[LDS_TOT];
    const int b = blockIdx.x, tid = threadIdx.x;
    const int l  = tid & 63;
    const int w  = __builtin_amdgcn_readfirstlane(tid >> 6);   // wave = head
    const int lc = l & 15, q4 = l >> 4;

    // ---- stage per-window scalars ----
    if (tid < NTOK){
        float u  = u_temp[b*NTOK + tid];
        float sg = 1.f / (1.f + __expf(-u));
        sm[LDS_RT + tid] = 0.17677669529663687f / (0.1f + 4.f*sg);   // (1/sqrt32)/T
        float ub = u_bias[b*NTOK + tid];
        sm[LDS_UB + tid] = ub > 0.f ? ub : 0.f;
    }
    if (tid < 196) sm[LDS_GATE + tid] = gate[b*196 + tid];
    __syncthreads();   // #1: the only pre-proj barrier

    const unsigned short* qkh = (const unsigned short*)ws;
    const unsigned short* qkl = qkh + 49152;

    // ---- phase A: QKV GEMM (split-bf16, 3 MFMAs). Wave w computes head w's q,k,v only.
    //      B-frags double-buffered: prefetch tile idx+1 while tile idx's MFMAs run. ----
    f4v vhold[2][4];   // v D-tiles [t][mt] held in regs
    #pragma unroll
    for (int mp = 0; mp < 2; ++mp){
        s8v ah[2][4], al[2][4];
        #pragma unroll
        for (int m2 = 0; m2 < 2; ++m2){
            int row = (mp*2 + m2)*16 + lc; if (row > 48) row = 48;
            const float* xp = x + ((size_t)b*NTOK + row)*128 + q4*8;
            #pragma unroll
            for (int kf = 0; kf < 4; ++kf){
                float xv[8];
                float4 t0 = *(const float4*)(xp + kf*32);
                float4 t1 = *(const float4*)(xp + kf*32 + 4);
                xv[0]=t0.x; xv[1]=t0.y; xv[2]=t0.z; xv[3]=t0.w;
                xv[4]=t1.x; xv[5]=t1.y; xv[6]=t1.z; xv[7]=t1.w;
                split8t(xv, ah[m2][kf], al[m2][kf]);
            }
        }
        s8v bhA[4], blA[4], bhB[4], blB[4];
        {   // preload tile 0 (g=0,t=0) into buffer A
            int col = (2*w)*16 + lc;
            #pragma unroll
            for (int kf = 0; kf < 4; ++kf){
                int off = col*128 + kf*32 + q4*8;
                bhA[kf] = *(const s8v*)(qkh + off);
                blA[kf] = *(const s8v*)(qkl + off);
            }
        }
        #pragma unroll
        for (int idx = 0; idx < 6; ++idx){
            const int g = idx >> 1, t = idx & 1;
            int nt  = (g==0 ? 2*w : (g==1 ? 8+2*w : 16+2*w)) + t;
            int col = nt*16 + lc;
            // prefetch next tile into the alternate buffer (compile-time parity)
            if (idx < 5){
                const int g2 = (idx+1) >> 1, t2 = (idx+1) & 1;
                int nt2  = (g2==0 ? 2*w : (g2==1 ? 8+2*w : 16+2*w)) + t2;
                int col2 = nt2*16 + lc;
                #pragma unroll
                for (int kf = 0; kf < 4; ++kf){
                    int off = col2*128 + kf*32 + q4*8;
                    if (idx & 1){ bhA[kf] = *(const s8v*)(qkh + off); blA[kf] = *(const s8v*)(qkl + off); }
                    else        { bhB[kf] = *(const s8v*)(qkh + off); blB[kf] = *(const s8v*)(qkl + off); }
                }
            }
            float bia = qkv_b[col];
            #pragma unroll
            for (int m2 = 0; m2 < 2; ++m2){
                f4v acc = {bia, bia, bia, bia};
                #pragma unroll
                for (int kf = 0; kf < 4; ++kf){
                    s8v bh = (idx & 1) ? bhB[kf] : bhA[kf];
                    s8v bl = (idx & 1) ? blB[kf] : blA[kf];
                    acc = MFMA(ah[m2][kf], bh, acc);
                    acc = MFMA(ah[m2][kf], bl, acc);
                    acc = MFMA(al[m2][kf], bh, acc);
                }
                int mt = mp*2 + m2;
                if (g == 2){
                    vhold[t][mt] = acc;
                } else {
                    #pragma unroll
                    for (int r = 0; r < 4; ++r){
                        int row = mt*16 + q4*4 + r;
                        if (row < NTOK){
                            if (g == 0) sm[LDS_Q + row*132 + col] = acc[r] * sm[LDS_RT + row];
                            else        sm[LDS_K + row*132 + (col - 128)] = acc[r];
                        }
                    }
                }
            }
        }
    }
    // no barrier: wave w reads only its own q/k columns below

    // ---- phase B: extract K/Q split-bf16 frags from own LDS cols ----
    s8v Kh[4], Kl[4], Qh[4], Ql[4];
    #pragma unroll
    for (int t = 0; t < 4; ++t){
        int row = 16*t + lc; if (row > 48) row = 48;
        float fv[8];
        {
            const float* p = &sm[LDS_K + row*132 + w*32 + q4*8];
            float4 a0 = *(const float4*)p; float4 a1 = *(const float4*)(p + 4);
            fv[0]=a0.x; fv[1]=a0.y; fv[2]=a0.z; fv[3]=a0.w;
            fv[4]=a1.x; fv[5]=a1.y; fv[6]=a1.z; fv[7]=a1.w;
            split8t(fv, Kh[t], Kl[t]);
        }
        {
            const float* p = &sm[LDS_Q + row*132 + w*32 + q4*8];
            float4 a0 = *(const float4*)p; float4 a1 = *(const float4*)(p + 4);
            fv[0]=a0.x; fv[1]=a0.y; fv[2]=a0.z; fv[3]=a0.w;
            fv[4]=a1.x; fv[5]=a1.y; fv[6]=a1.z; fv[7]=a1.w;
            split8t(fv, Qh[t], Ql[t]);
        }
    }

    // ---- S^T = K·Q^T, streamed per query-tile nt (S live = 16 regs) ----
    const float* biasT = (const float*)((const char*)ws + WS_BIAS_OFF);
    unsigned short* P = (unsigned short*)sm;   // bf16 P overlays LDS_Q (Q frags already in regs)
    #pragma unroll
    for (int nt = 0; nt < 4; ++nt){
        int qy = nt*16 + lc;
        int qyc = qy > 48 ? 48 : qy;
        f4v S[4];
        #pragma unroll
        for (int mt = 0; mt < 4; ++mt){
            f4v a;
            #pragma unroll
            for (int r = 0; r < 4; ++r){
                int ky = mt*16 + q4*4 + r; if (ky > 48) ky = 48;
                // K-MAJOR bias: lane-contiguous in qyc -> 4x64B segments per load instr
                a[r] = biasT[w*2401 + ky*49 + qyc] - sm[LDS_UB + ky];
            }
            a = MFMA(Kh[mt], Qh[nt], a);
            a = MFMA(Kh[mt], Ql[nt], a);
            a = MFMA(Kl[mt], Qh[nt], a);
            S[mt] = a;
        }
        #pragma unroll
        for (int r = 0; r < 4; ++r){
            int ky = 48 + q4*4 + r;
            if (ky >= NTOK) S[3][r] = -1e30f;
        }
        float mx = -3e38f;
        #pragma unroll
        for (int mt = 0; mt < 4; ++mt)
            #pragma unroll
            for (int r = 0; r < 4; ++r) mx = fmaxf(mx, S[mt][r]);
        mx = fmaxf(mx, __shfl_xor(mx, 16));
        mx = fmaxf(mx, __shfl_xor(mx, 32));
        float sum = 0.f;
        #pragma unroll
        for (int mt = 0; mt < 4; ++mt)
            #pragma unroll
            for (int r = 0; r < 4; ++r){
                float e = __expf(S[mt][r] - mx);
                S[mt][r] = e; sum += e;
            }
        sum += __shfl_xor(sum, 16);
        sum += __shfl_xor(sum, 32);
        float rs = 1.f / sum;
        // ---- write P (bf16, q-slot cols 32w as u16 pairs, XOR-swizzled) ----
        if (qy < NTOK){
            #pragma unroll
            for (int mt = 0; mt < 4; ++mt)
                #pragma unroll
                for (int r = 0; r < 4; ++r){
                    int ky = mt*16 + q4*4 + r;
                    P[(qy*132 + w*32)*2 + (((ky>>3) ^ (qy&7)) << 3) + (ky&7)] = f2bf(S[mt][r] * rs);
                }
        }
    }
    // no barrier: overlays below touch only wave w's own columns

    // ---- stage v (fp32, k-slot cols 32w; k frags already in regs) ----
    #pragma unroll
    for (int t = 0; t < 2; ++t)
        #pragma unroll
        for (int mt = 0; mt < 4; ++mt)
            #pragma unroll
            for (int r = 0; r < 4; ++r){
                int row = mt*16 + q4*4 + r;
                if (row < NTOK) sm[LDS_K + row*132 + w*32 + t*16 + lc] = vhold[t][mt][r];
            }

    // ---- PV (same-wave LDS round trip) ----
    s8v Pa[4][2];
    #pragma unroll
    for (int mt = 0; mt < 4; ++mt)
        #pragma unroll
        for (int kf = 0; kf < 2; ++kf){
            int qy = mt*16 + lc; if (qy > 48) qy = 48;
            int ch = (4*kf + q4) ^ (qy & 7);
            Pa[mt][kf] = *(const s8v*)(P + (qy*132 + w*32)*2 + ch*8);
        }
    s8v Vb[2][2];
    #pragma unroll
    for (int t = 0; t < 2; ++t)
        #pragma unroll
        for (int kf = 0; kf < 2; ++kf){
            #pragma unroll
            for (int j = 0; j < 8; ++j){
                int key = kf*32 + q4*8 + j; if (key > 48) key = 48;
                Vb[t][kf][j] = (short)(__float_as_uint(sm[LDS_K + key*132 + w*32 + t*16 + lc]) >> 16);
            }
        }
    f4v O[4][2];
    #pragma unroll
    for (int mt = 0; mt < 4; ++mt)
        #pragma unroll
        for (int t = 0; t < 2; ++t){
            f4v o = {0.f, 0.f, 0.f, 0.f};
            o = MFMA(Pa[mt][0], Vb[t][0], o);
            o = MFMA(Pa[mt][1], Vb[t][1], o);
            O[mt][t] = o;
        }
    // no barrier: attn write below goes to wave w's own k-slot columns (own v, now dead)

    // ---- hoist proj B-frags + proj_b NOW (global-only, independent of LDS):
    //      latency hides under attn staging + barrier wait ----
    const unsigned short* ph = (const unsigned short*)((const char*)ws + 196608);
    const unsigned short* pl = (const unsigned short*)((const char*)ws + 229376);
    s8v Bh[2][4], Bl[2][4];
    float biaP[2];
    #pragma unroll
    for (int t = 0; t < 2; ++t){
        int col = (2*w + t)*16 + lc;
        #pragma unroll
        for (int kf = 0; kf < 4; ++kf){
            int off = col*128 + kf*32 + q4*8;
            Bh[t][kf] = *(const s8v*)(ph + off);
            Bl[t][kf] = *(const s8v*)(pl + off);
        }
        biaP[t] = proj_b[col];
    }

    // ---- gate + stage attn_out pre-split: hi u16[0..31] then lo u16[0..31] per row, in k-cols 32w ----
    #pragma unroll
    for (int mt = 0; mt < 4; ++mt)
        #pragma unroll
        for (int t = 0; t < 2; ++t)
            #pragma unroll
            for (int r = 0; r < 4; ++r){
                int row = mt*16 + q4*4 + r;
                if (row < NTOK){
                    float vg = O[mt][t][r] * sm[LDS_GATE + w*49 + row];
                    unsigned u = __float_as_uint(vg);
                    float res = vg - __uint_as_float(u & 0xffff0000u);
                    char* bp = (char*)sm + (LDS_K + row*132 + w*32)*4;
                    ((unsigned short*)bp)[t*16 + lc]        = (unsigned short)(u >> 16);
                    ((unsigned short*)(bp + 64))[t*16 + lc] = (unsigned short)(__float_as_uint(res) >> 16);
                }
            }
    __syncthreads();   // #2: the single cross-wave handoff (all heads' attn_out -> proj)

    // ---- proj GEMM (split-bf16, 3 MFMAs); A-frags: head kf's block = k-cols 32*kf ----
    #pragma unroll
    for (int mt = 0; mt < 4; ++mt){
        int row = mt*16 + lc; if (row > 48) row = 48;
        s8v Ah[4], Al[4];
        #pragma unroll
        for (int kf = 0; kf < 4; ++kf){
            const char* bp = (const char*)sm + (LDS_K + row*132 + kf*32)*4;
            Ah[kf] = *(const s8v*)(bp + q4*16);
            Al[kf] = *(const s8v*)(bp + 64 + q4*16);
        }
        #pragma unroll
        for (int t = 0; t < 2; ++t){
            int col = (2*w + t)*16 + lc;
            f4v acc = {biaP[t], biaP[t], biaP[t], biaP[t]};
            #pragma unroll
            for (int kf = 0; kf < 4; ++kf){
                acc = MFMA(Ah[kf], Bh[t][kf], acc);
                acc = MFMA(Ah[kf], Bl[t][kf], acc);
                acc = MFMA(Al[kf], Bh[t][kf], acc);
            }
            #pragma unroll
            for (int r = 0; r < 4; ++r){
                int r2 = mt*16 + q4*4 + r;
                if (r2 < NTOK) out[((size_t)b*NTOK + r2)*128 + col] = acc[r];
            }
        }
    }
}

extern "C" void kernel_launch(void* const* d_in, const int* in_sizes, int n_in,
                              void* d_out, int out_size, void* d_ws, size_t ws_size,
                              hipStream_t stream) {
    const float* x  = (const float*)d_in[0];
    const float* ut = (const float*)d_in[1];
    const float* ub = (const float*)d_in[2];
    const float* tg = (const float*)d_in[3];
    const float* qw = (const float*)d_in[4];
    const float* qb = (const float*)d_in[5];
    const float* pw = (const float*)d_in[6];
    const float* pb = (const float*)d_in[7];
    const float* rt = (const float*)d_in[8];
    const int*   ri = (const int*)d_in[9];
    float* o = (float*)d_out;
    const int B = in_sizes[0] / (NTOK * 128);

    prep_kernel<<<294, 256, 0, stream>>>(qw, pw, rt, ri, d_ws);
    win_attn<<<B, 256, 0, stream>>>(x, ut, ub, tg, qb, pb, d_ws, o);
}